// Round 5
// baseline (595.875 us; speedup 1.0000x reference)
//
#include <hip/hip_runtime.h>
#include <math.h>

#define BATCH 2
#define LSEQ  2048
#define EMB   2048
#define NH    16
#define HD    128

typedef __attribute__((ext_vector_type(8))) short bf16x8;
typedef __attribute__((ext_vector_type(8))) unsigned short u16x8;
typedef __attribute__((ext_vector_type(4))) float f32x4;

static __device__ __forceinline__ unsigned short f2bf(float f) {
    unsigned u = __float_as_uint(f);
    u += 0x7fffu + ((u >> 16) & 1u);
    return (unsigned short)(u >> 16);
}

// async global->LDS, 16 bytes per lane; LDS dest must be wave-uniform base + lane*16
static __device__ __forceinline__ void load_lds16(const void* g, void* l) {
    __builtin_amdgcn_global_load_lds(
        (const __attribute__((address_space(1))) void*)g,
        (__attribute__((address_space(3))) void*)l, 16, 0, 0);
}

// ---------------------------------------------------------------------------
// cast fp32 -> bf16 for x, w_attn, w_proj
// ---------------------------------------------------------------------------
#define N1 (BATCH * LSEQ * EMB)      // 8388608  (x)
#define N2 (3 * EMB * EMB)           // 12582912 (w_attn)
#define N3 (EMB * EMB)               // 4194304  (w_proj)

__global__ __launch_bounds__(256) void cast_bf16_kernel(
    const float* __restrict__ x, const float* __restrict__ wa,
    const float* __restrict__ wp,
    unsigned short* __restrict__ xb, unsigned short* __restrict__ wab,
    unsigned short* __restrict__ wpb)
{
    size_t i4 = ((size_t)blockIdx.x * 256 + threadIdx.x) * 4;
    const float* src;
    unsigned short* dst;
    size_t off;
    if (i4 < (size_t)N1) { src = x; dst = xb; off = i4; }
    else if (i4 < (size_t)N1 + N2) { src = wa; dst = wab; off = i4 - N1; }
    else { src = wp; dst = wpb; off = i4 - N1 - N2; }
    float4 f = *(const float4*)(src + off);
    ushort4 u;
    u.x = f2bf(f.x); u.y = f2bf(f.y); u.z = f2bf(f.z); u.w = f2bf(f.w);
    *(ushort4*)(dst + off) = u;
}

// ---------------------------------------------------------------------------
// MFMA bf16 GEMM: C[m,n] = sum_k A[m,k]*B[n,k]  (A MxK, B NxK, row-major bf16)
// mode 0: C fp32 row-major [M,N]
// mode 1: q/k scattered bf16 into [B,H,L,HD] WITH RoPE fused;
//         v scattered bf16 TRANSPOSED into [B,H,HD,L] (packed ushort4 along L)
// ---------------------------------------------------------------------------
__global__ __launch_bounds__(256) void gemm_bt_bf16(
    const unsigned short* __restrict__ A, const unsigned short* __restrict__ B,
    const float* __restrict__ rope,
    float* __restrict__ C,
    unsigned short* __restrict__ qo, unsigned short* __restrict__ ko,
    unsigned short* __restrict__ vo,
    int M, int N, int K, int mode)
{
    __shared__ unsigned short As[128 * 64];  // 16 KB
    __shared__ unsigned short Bs[128 * 64];  // 16 KB

    const int tid = threadIdx.x;
    const int lane = tid & 63;
    const int w = tid >> 6;
    const int m = lane & 15;
    const int g = lane >> 4;
    const int wm = (w & 1) * 64;
    const int wn = (w >> 1) * 64;
    const int bm = blockIdx.y * 128;
    const int bn = blockIdx.x * 128;

    const int srow = tid >> 3;
    const int scol = (tid & 7) * 8;

    f32x4 acc[4][4];
#pragma unroll
    for (int mi = 0; mi < 4; mi++)
#pragma unroll
        for (int ni = 0; ni < 4; ni++) acc[mi][ni] = (f32x4){0.f, 0.f, 0.f, 0.f};

    for (int k0 = 0; k0 < K; k0 += 64) {
        __syncthreads();
#pragma unroll
        for (int i = 0; i < 4; i++) {
            const int row = i * 32 + srow;
            load_lds16(A + (size_t)(bm + row) * K + k0 + scol, &As[row * 64 + scol]);
            load_lds16(B + (size_t)(bn + row) * K + k0 + scol, &Bs[row * 64 + scol]);
        }
        __syncthreads();

#pragma unroll
        for (int kc = 0; kc < 2; kc++) {
            bf16x8 af[4], bfv[4];
#pragma unroll
            for (int mi = 0; mi < 4; mi++)
                af[mi] = *(const bf16x8*)&As[(wm + mi * 16 + m) * 64 + kc * 32 + g * 8];
#pragma unroll
            for (int ni = 0; ni < 4; ni++)
                bfv[ni] = *(const bf16x8*)&Bs[(wn + ni * 16 + m) * 64 + kc * 32 + g * 8];
#pragma unroll
            for (int mi = 0; mi < 4; mi++)
#pragma unroll
                for (int ni = 0; ni < 4; ni++)
                    acc[mi][ni] = __builtin_amdgcn_mfma_f32_16x16x32_bf16(
                        af[mi], bfv[ni], acc[mi][ni], 0, 0, 0);
        }
    }

    // epilogue: C/D layout col=lane&15, row=g*4+reg
#pragma unroll
    for (int mi = 0; mi < 4; mi++) {
#pragma unroll
        for (int ni = 0; ni < 4; ni++) {
            const int col = bn + wn + ni * 16 + m;
            if (mode == 0) {
#pragma unroll
                for (int r = 0; r < 4; r++) {
                    const int row = bm + wm + mi * 16 + g * 4 + r;
                    C[(size_t)row * N + col] = acc[mi][ni][r];
                }
            } else {
                const int which = col >> 11;          // wave-uniform
                const int e = col & 2047;
                const int h = e >> 7;
                const int d = e & 127;
                if (which < 2) {
                    // q/k with fused RoPE: pair (even d, odd d) across lanes m, m^1
                    unsigned short* dst = (which == 0) ? qo : ko;
                    const int t2 = ((d >> 1) << 1);   // pair index *2
#pragma unroll
                    for (int r = 0; r < 4; r++) {
                        const int row = bm + wm + mi * 16 + g * 4 + r;
                        const int b = row >> 11;
                        const int l = row & 2047;
                        float val = acc[mi][ni][r];
                        const float prt = __shfl_xor(val, 1);
                        const float2 sc = *(const float2*)(rope + (size_t)l * HD + t2);
                        val = (m & 1) ? fmaf(val, sc.y, prt * sc.x)
                                      : fmaf(val, sc.y, -prt * sc.x);
                        dst[(((size_t)(b * NH + h)) * LSEQ + l) * HD + d] = f2bf(val);
                    }
                } else {
                    // v transposed: [B,H,HD,L], 4 consecutive l per lane -> ushort4
                    const int l0 = bm + wm + mi * 16 + g * 4;
                    const int b = l0 >> 11;
                    const int l = l0 & 2047;
                    ushort4 vv;
                    vv.x = f2bf(acc[mi][ni][0]);
                    vv.y = f2bf(acc[mi][ni][1]);
                    vv.z = f2bf(acc[mi][ni][2]);
                    vv.w = f2bf(acc[mi][ni][3]);
                    *(ushort4*)(vo + (((size_t)(b * NH + h)) * HD + d) * LSEQ + l) = vv;
                }
            }
        }
    }
}

// ---------------------------------------------------------------------------
// MFMA bf16 flash attention (causal).
// q,k: [B*H, L, HD] bf16; vT: [B*H, HD, L] bf16; y: [B, L, H, HD] bf16.
// Grid: (32 q-tiles interleaved light/heavy, 32 bh). Block 256 = 4 waves,
// each wave owns 16 q-rows. Q frags in registers. K and Vt tiles staged in
// LDS via global_load_lds (16B lane-linear copies). Ps = per-wave P
// C-layout -> A-layout round trip. LDS 41 KB -> 3 blocks/CU.
// ---------------------------------------------------------------------------
#define PTILES 32     // LSEQ / 64
#define PS_STR 68

__global__ __launch_bounds__(256) void attn_kernel(
    const unsigned short* __restrict__ q, const unsigned short* __restrict__ k,
    const unsigned short* __restrict__ vT, unsigned short* __restrict__ y)
{
    __shared__ unsigned short Ks[64 * 128];     // 16 KB  [key][d]
    __shared__ unsigned short Vs[128 * 64];     // 16 KB  [d][key]
    __shared__ unsigned short Ps[64 * PS_STR];  // 8704 B

    const int tid = threadIdx.x;
    const int lane = tid & 63;
    const int w = tid >> 6;
    const int m = lane & 15;
    const int g = lane >> 4;
    const int bx = blockIdx.x;
    // interleave: 0,31,1,30,2,29,... so heavy tiles don't cluster in dispatch
    const int qt = (bx & 1) ? (PTILES - 1 - (bx >> 1)) : (bx >> 1);
    const int bh = blockIdx.y;
    const int q0 = qt * 64;
    const size_t base = (size_t)bh * LSEQ * HD;   // also [bh][HD][LSEQ] base for vT
    const float scale = 0.08838834764831845f;  // 1/sqrt(128)
    const int bB = bh / NH;
    const int hh = bh % NH;

    // ---- Q fragments in registers (row = q0 + w*16 + m) ----
    bf16x8 aq[4];
    {
        const unsigned short* qrow = q + base + (size_t)(q0 + w * 16 + m) * HD;
#pragma unroll
        for (int kc = 0; kc < 4; kc++)
            aq[kc] = *(const bf16x8*)(qrow + kc * 32 + g * 8);
    }

    f32x4 o[8];
#pragma unroll
    for (int i = 0; i < 8; i++) o[i] = (f32x4){0.f, 0.f, 0.f, 0.f};
    float mprev[4], lsum[4];
#pragma unroll
    for (int r = 0; r < 4; r++) { mprev[r] = -1e30f; lsum[r] = 0.f; }

    for (int kt = 0; kt <= qt; kt++) {
        const int k0 = kt * 64;

        __syncthreads();  // previous-iter LDS frag reads done
        // stage K tile: global rows k0..k0+63 are one contiguous 16 KB region
        {
            const unsigned short* ksrc = k + base + (size_t)k0 * HD;
#pragma unroll
            for (int i = 0; i < 4; i++)
                load_lds16(ksrc + ((i * 256 + tid) * 8), &Ks[(i * 256 + tid) * 8]);
        }
        // stage Vt tile: 128 rows (d) x 64 keys, global row stride LSEQ
        {
#pragma unroll
            for (int i = 0; i < 4; i++) {
                const int idx = i * 256 + tid;
                const int d = idx >> 3;
                const int c = (idx & 7) * 8;
                load_lds16(vT + base + (size_t)d * LSEQ + k0 + c, &Vs[d * 64 + c]);
            }
        }
        __syncthreads();  // staging complete (vmcnt drained by barrier)

        // ---- S = Q K^T (16 rows x 64 keys per wave) ----
        f32x4 s[4];
#pragma unroll
        for (int n = 0; n < 4; n++) {
            f32x4 acc = (f32x4){0.f, 0.f, 0.f, 0.f};
#pragma unroll
            for (int kc = 0; kc < 4; kc++) {
                bf16x8 bk = *(const bf16x8*)&Ks[(n * 16 + m) * 128 + kc * 32 + g * 8];
                acc = __builtin_amdgcn_mfma_f32_16x16x32_bf16(aq[kc], bk, acc, 0, 0, 0);
            }
            s[n] = acc;
        }

        // ---- scale + causal mask (only the diagonal tile) ----
        const int rowg = q0 + w * 16 + g * 4;
        if (kt == qt) {
#pragma unroll
            for (int n = 0; n < 4; n++) {
                const int col = k0 + n * 16 + m;
#pragma unroll
                for (int r = 0; r < 4; r++) {
                    const float val = s[n][r] * scale;
                    s[n][r] = (col <= rowg + r) ? val : -1e30f;
                }
            }
        } else {
#pragma unroll
            for (int n = 0; n < 4; n++)
#pragma unroll
                for (int r = 0; r < 4; r++) s[n][r] *= scale;
        }

        // ---- online softmax ----
        float al[4];
#pragma unroll
        for (int r = 0; r < 4; r++) {
            float v0 = fmaxf(fmaxf(s[0][r], s[1][r]), fmaxf(s[2][r], s[3][r]));
            v0 = fmaxf(v0, __shfl_xor(v0, 1));
            v0 = fmaxf(v0, __shfl_xor(v0, 2));
            v0 = fmaxf(v0, __shfl_xor(v0, 4));
            v0 = fmaxf(v0, __shfl_xor(v0, 8));
            const float mn = fmaxf(mprev[r], v0);
            al[r] = __expf(mprev[r] - mn);
            mprev[r] = mn;
        }
#pragma unroll
        for (int r = 0; r < 4; r++) {
            float sum = 0.f;
#pragma unroll
            for (int n = 0; n < 4; n++) {
                const float p = __expf(s[n][r] - mprev[r]);
                sum += p;
                Ps[(w * 16 + g * 4 + r) * PS_STR + n * 16 + m] = f2bf(p);
            }
            sum += __shfl_xor(sum, 1);
            sum += __shfl_xor(sum, 2);
            sum += __shfl_xor(sum, 4);
            sum += __shfl_xor(sum, 8);
            lsum[r] = lsum[r] * al[r] + sum;
        }

        // ---- O = O*alpha + P V ----
#pragma unroll
        for (int dc = 0; dc < 8; dc++)
#pragma unroll
            for (int r = 0; r < 4; r++) o[dc][r] *= al[r];

        // per-wave private Ps rows; same-wave DS ordering suffices (no barrier)
        bf16x8 ap[2];
#pragma unroll
        for (int kk = 0; kk < 2; kk++)
            ap[kk] = *(const bf16x8*)&Ps[(w * 16 + m) * PS_STR + kk * 32 + g * 8];
#pragma unroll
        for (int dc = 0; dc < 8; dc++) {
#pragma unroll
            for (int kk = 0; kk < 2; kk++) {
                bf16x8 bv = *(const bf16x8*)&Vs[(dc * 16 + m) * 64 + kk * 32 + g * 8];
                o[dc] = __builtin_amdgcn_mfma_f32_16x16x32_bf16(ap[kk], bv, o[dc], 0, 0, 0);
            }
        }
    }

    // ---- epilogue: normalize, write y bf16 [B, L, H, HD] ----
#pragma unroll
    for (int r = 0; r < 4; r++) {
        const float inv = 1.f / lsum[r];
        const int lrow = q0 + w * 16 + g * 4 + r;
        unsigned short* dst = y + (((size_t)bB * LSEQ + lrow) * NH + hh) * HD;
#pragma unroll
        for (int dc = 0; dc < 8; dc++)
            dst[dc * 16 + m] = f2bf(o[dc][r] * inv);
    }
}

// ---------------------------------------------------------------------------
extern "C" void kernel_launch(void* const* d_in, const int* in_sizes, int n_in,
                              void* d_out, int out_size, void* d_ws, size_t ws_size,
                              hipStream_t stream) {
    const float* x      = (const float*)d_in[0];
    const float* rope   = (const float*)d_in[1];
    const float* w_attn = (const float*)d_in[2];
    const float* w_proj = (const float*)d_in[3];
    float* out = (float*)d_out;
    unsigned short* ws = (unsigned short*)d_ws;

    const size_t per = (size_t)BATCH * NH * LSEQ * HD;  // 8,388,608
    unsigned short* qb  = ws;
    unsigned short* kb  = ws + per;
    unsigned short* vb  = ws + 2 * per;   // transposed layout [B,H,HD,L]
    unsigned short* yb  = ws + 3 * per;
    unsigned short* xb  = ws + 4 * per;
    unsigned short* wab = xb + (size_t)N1;
    unsigned short* wpb = wab + (size_t)N2;

    const int M = BATCH * LSEQ;  // 4096

    // 0) cast inputs to bf16
    const int cast_blocks = (N1 + N2 + N3) / 4 / 256;
    cast_bf16_kernel<<<cast_blocks, 256, 0, stream>>>(x, w_attn, w_proj, xb, wab, wpb);

    // 1) QKV projection (MFMA bf16) + fused RoPE; v written transposed
    dim3 g1(3 * EMB / 128, M / 128);  // (48, 32)
    gemm_bt_bf16<<<g1, 256, 0, stream>>>(xb, wab, rope, nullptr, qb, kb, vb,
                                         M, 3 * EMB, EMB, 1);

    // 2) causal flash attention -> y bf16
    dim3 ga(PTILES, BATCH * NH);  // (32, 32)
    attn_kernel<<<ga, 256, 0, stream>>>(qb, kb, vb, yb);

    // 3) output projection (MFMA bf16) -> fp32 out
    dim3 g2(EMB / 128, M / 128);  // (16, 32)
    gemm_bt_bf16<<<g2, 256, 0, stream>>>(yb, wpb, nullptr, out,
                                         nullptr, nullptr, nullptr, M, EMB, EMB, 0);
}

// Round 7
// 469.198 us; speedup vs baseline: 1.2700x; 1.2700x over previous
//
#include <hip/hip_runtime.h>
#include <math.h>

#define BATCH 2
#define LSEQ  2048
#define EMB   2048
#define NH    16
#define HD    128

typedef __attribute__((ext_vector_type(8))) short bf16x8;
typedef __attribute__((ext_vector_type(8))) unsigned short u16x8;
typedef __attribute__((ext_vector_type(4))) float f32x4;

static __device__ __forceinline__ unsigned short f2bf(float f) {
    unsigned u = __float_as_uint(f);
    u += 0x7fffu + ((u >> 16) & 1u);
    return (unsigned short)(u >> 16);
}

// async global->LDS, 16 bytes per lane; LDS dest must be wave-uniform base + lane*16
static __device__ __forceinline__ void load_lds16(const void* g, void* l) {
    __builtin_amdgcn_global_load_lds(
        (const __attribute__((address_space(1))) void*)g,
        (__attribute__((address_space(3))) void*)l, 16, 0, 0);
}

// ---------------------------------------------------------------------------
// cast fp32 -> bf16 for x, w_attn, w_proj
// ---------------------------------------------------------------------------
#define N1 (BATCH * LSEQ * EMB)      // 8388608  (x)
#define N2 (3 * EMB * EMB)           // 12582912 (w_attn)
#define N3 (EMB * EMB)               // 4194304  (w_proj)

__global__ __launch_bounds__(256) void cast_bf16_kernel(
    const float* __restrict__ x, const float* __restrict__ wa,
    const float* __restrict__ wp,
    unsigned short* __restrict__ xb, unsigned short* __restrict__ wab,
    unsigned short* __restrict__ wpb)
{
    size_t i4 = ((size_t)blockIdx.x * 256 + threadIdx.x) * 4;
    const float* src;
    unsigned short* dst;
    size_t off;
    if (i4 < (size_t)N1) { src = x; dst = xb; off = i4; }
    else if (i4 < (size_t)N1 + N2) { src = wa; dst = wab; off = i4 - N1; }
    else { src = wp; dst = wpb; off = i4 - N1 - N2; }
    float4 f = *(const float4*)(src + off);
    ushort4 u;
    u.x = f2bf(f.x); u.y = f2bf(f.y); u.z = f2bf(f.z); u.w = f2bf(f.w);
    *(ushort4*)(dst + off) = u;
}

// ---------------------------------------------------------------------------
// MFMA bf16 GEMM: C[m,n] = sum_k A[m,k]*B[n,k]  (A MxK, B NxK, row-major bf16)
// LDS staging is XOR-swizzled: LDS 16B-chunk slot row*8+c' holds global chunk
// c = c' ^ (row&7). Reads use the matching swizzle -> uniform bank quads.
// mode 0: C fp32 row-major [M,N]
// mode 1: q/k scattered bf16 into [B,H,L,HD] WITH RoPE fused;
//         v scattered bf16 TRANSPOSED into [B,H,HD,L] (packed ushort4 along L)
// ---------------------------------------------------------------------------
__global__ __launch_bounds__(256) void gemm_bt_bf16(
    const unsigned short* __restrict__ A, const unsigned short* __restrict__ B,
    const float* __restrict__ rope,
    float* __restrict__ C,
    unsigned short* __restrict__ qo, unsigned short* __restrict__ ko,
    unsigned short* __restrict__ vo,
    int M, int N, int K, int mode)
{
    __shared__ unsigned short As[128 * 64];  // 16 KB
    __shared__ unsigned short Bs[128 * 64];  // 16 KB

    const int tid = threadIdx.x;
    const int lane = tid & 63;
    const int w = tid >> 6;
    const int m = lane & 15;
    const int g = lane >> 4;
    const int wm = (w & 1) * 64;
    const int wn = (w >> 1) * 64;
    const int bm = blockIdx.y * 128;
    const int bn = blockIdx.x * 128;

    f32x4 acc[4][4];
#pragma unroll
    for (int mi = 0; mi < 4; mi++)
#pragma unroll
        for (int ni = 0; ni < 4; ni++) acc[mi][ni] = (f32x4){0.f, 0.f, 0.f, 0.f};

    for (int k0 = 0; k0 < K; k0 += 64) {
        __syncthreads();
#pragma unroll
        for (int i = 0; i < 4; i++) {
            const int idx = i * 256 + tid;          // lane-linear LDS 16B slot
            const int row = idx >> 3;               // 0..127
            const int c = (idx & 7) ^ (row & 7);    // swizzled source chunk
            load_lds16(A + (size_t)(bm + row) * K + k0 + c * 8, &As[idx * 8]);
            load_lds16(B + (size_t)(bn + row) * K + k0 + c * 8, &Bs[idx * 8]);
        }
        __syncthreads();

#pragma unroll
        for (int kc = 0; kc < 2; kc++) {
            bf16x8 af[4], bfv[4];
#pragma unroll
            for (int mi = 0; mi < 4; mi++) {
                const int row = wm + mi * 16 + m;
                af[mi] = *(const bf16x8*)&As[(row * 8 + ((kc * 4 + g) ^ (m & 7))) * 8];
            }
#pragma unroll
            for (int ni = 0; ni < 4; ni++) {
                const int row = wn + ni * 16 + m;
                bfv[ni] = *(const bf16x8*)&Bs[(row * 8 + ((kc * 4 + g) ^ (m & 7))) * 8];
            }
#pragma unroll
            for (int mi = 0; mi < 4; mi++)
#pragma unroll
                for (int ni = 0; ni < 4; ni++)
                    acc[mi][ni] = __builtin_amdgcn_mfma_f32_16x16x32_bf16(
                        af[mi], bfv[ni], acc[mi][ni], 0, 0, 0);
        }
    }

    // epilogue: C/D layout col=lane&15, row=g*4+reg
#pragma unroll
    for (int mi = 0; mi < 4; mi++) {
#pragma unroll
        for (int ni = 0; ni < 4; ni++) {
            const int col = bn + wn + ni * 16 + m;
            if (mode == 0) {
#pragma unroll
                for (int r = 0; r < 4; r++) {
                    const int row = bm + wm + mi * 16 + g * 4 + r;
                    C[(size_t)row * N + col] = acc[mi][ni][r];
                }
            } else {
                const int which = col >> 11;          // wave-uniform
                const int e = col & 2047;
                const int h = e >> 7;
                const int d = e & 127;
                if (which < 2) {
                    // q/k with fused RoPE: pair (even d, odd d) across lanes m, m^1
                    unsigned short* dst = (which == 0) ? qo : ko;
                    const int t2 = ((d >> 1) << 1);   // pair index *2
#pragma unroll
                    for (int r = 0; r < 4; r++) {
                        const int row = bm + wm + mi * 16 + g * 4 + r;
                        const int b = row >> 11;
                        const int l = row & 2047;
                        float val = acc[mi][ni][r];
                        const float prt = __shfl_xor(val, 1);
                        const float2 sc = *(const float2*)(rope + (size_t)l * HD + t2);
                        val = (m & 1) ? fmaf(val, sc.y, prt * sc.x)
                                      : fmaf(val, sc.y, -prt * sc.x);
                        dst[(((size_t)(b * NH + h)) * LSEQ + l) * HD + d] = f2bf(val);
                    }
                } else {
                    // v transposed: [B,H,HD,L], 4 consecutive l per lane -> ushort4
                    const int l0 = bm + wm + mi * 16 + g * 4;
                    const int b = l0 >> 11;
                    const int l = l0 & 2047;
                    ushort4 vv;
                    vv.x = f2bf(acc[mi][ni][0]);
                    vv.y = f2bf(acc[mi][ni][1]);
                    vv.z = f2bf(acc[mi][ni][2]);
                    vv.w = f2bf(acc[mi][ni][3]);
                    *(ushort4*)(vo + (((size_t)(b * NH + h)) * HD + d) * LSEQ + l) = vv;
                }
            }
        }
    }
}

// ---------------------------------------------------------------------------
// MFMA bf16 flash attention (causal).
// q,k: [B*H, L, HD] bf16; vT: [B*H, HD, L] bf16; y: [B, L, H, HD] bf16.
// K/Vt staged in LDS via global_load_lds with XOR-swizzled chunk layout:
//   Ks: slot row*16 + c'  holds K[row][c' ^ (row&7)]   (16 chunks/row)
//   Vs: slot d*8 + c'     holds Vt[d][c' ^ (d&7)]      (8 chunks/row)
// Fragment reads apply the same swizzle -> uniform bank-quad distribution.
// Ps keeps the round-4 zero-conflict layout (stride 68).
// ---------------------------------------------------------------------------
#define PTILES 32     // LSEQ / 64
#define PS_STR 68

__global__ __launch_bounds__(256) void attn_kernel(
    const unsigned short* __restrict__ q, const unsigned short* __restrict__ k,
    const unsigned short* __restrict__ vT, unsigned short* __restrict__ y)
{
    __shared__ unsigned short Ks[64 * 128];     // 16 KB  [key][d] swizzled
    __shared__ unsigned short Vs[128 * 64];     // 16 KB  [d][key] swizzled
    __shared__ unsigned short Ps[64 * PS_STR];  // 8704 B

    const int tid = threadIdx.x;
    const int lane = tid & 63;
    const int w = tid >> 6;
    const int m = lane & 15;
    const int g = lane >> 4;
    const int bx = blockIdx.x;
    // interleave: 0,31,1,30,2,29,... so heavy tiles don't cluster in dispatch
    const int qt = (bx & 1) ? (PTILES - 1 - (bx >> 1)) : (bx >> 1);
    const int bh = blockIdx.y;
    const int q0 = qt * 64;
    const size_t base = (size_t)bh * LSEQ * HD;   // also [bh][HD][LSEQ] base for vT
    const float scale = 0.08838834764831845f;  // 1/sqrt(128)
    const int bB = bh / NH;
    const int hh = bh % NH;
    const int sw = m & 7;   // read-side swizzle key

    // ---- Q fragments in registers (row = q0 + w*16 + m) ----
    bf16x8 aq[4];
    {
        const unsigned short* qrow = q + base + (size_t)(q0 + w * 16 + m) * HD;
#pragma unroll
        for (int kc = 0; kc < 4; kc++)
            aq[kc] = *(const bf16x8*)(qrow + kc * 32 + g * 8);
    }

    f32x4 o[8];
#pragma unroll
    for (int i = 0; i < 8; i++) o[i] = (f32x4){0.f, 0.f, 0.f, 0.f};
    float mprev[4], lsum[4];
#pragma unroll
    for (int r = 0; r < 4; r++) { mprev[r] = -1e30f; lsum[r] = 0.f; }

    for (int kt = 0; kt <= qt; kt++) {
        const int k0 = kt * 64;

        __syncthreads();  // previous-iter LDS frag reads done
        // stage K tile (swizzled source, lane-linear LDS dest)
        {
            const unsigned short* ksrc = k + base + (size_t)k0 * HD;
#pragma unroll
            for (int i = 0; i < 4; i++) {
                const int idx = i * 256 + tid;
                const int row = idx >> 4;                 // 0..63
                const int c = (idx & 15) ^ (row & 7);     // source chunk
                load_lds16(ksrc + (size_t)row * HD + c * 8, &Ks[idx * 8]);
            }
        }
        // stage Vt tile (swizzled)
        {
#pragma unroll
            for (int i = 0; i < 4; i++) {
                const int idx = i * 256 + tid;
                const int d = idx >> 3;                   // 0..127
                const int c = (idx & 7) ^ (d & 7);
                load_lds16(vT + base + (size_t)d * LSEQ + k0 + c * 8, &Vs[idx * 8]);
            }
        }
        __syncthreads();  // staging complete

        // ---- S = Q K^T (16 rows x 64 keys per wave) ----
        f32x4 s[4];
#pragma unroll
        for (int n = 0; n < 4; n++) {
            f32x4 acc = (f32x4){0.f, 0.f, 0.f, 0.f};
#pragma unroll
            for (int kc = 0; kc < 4; kc++) {
                const int row = n * 16 + m;
                bf16x8 bk = *(const bf16x8*)&Ks[(row * 16 + ((kc * 4 + g) ^ sw)) * 8];
                acc = __builtin_amdgcn_mfma_f32_16x16x32_bf16(aq[kc], bk, acc, 0, 0, 0);
            }
            s[n] = acc;
        }

        // ---- scale + causal mask (only the diagonal tile) ----
        const int rowg = q0 + w * 16 + g * 4;
        if (kt == qt) {
#pragma unroll
            for (int n = 0; n < 4; n++) {
                const int col = k0 + n * 16 + m;
#pragma unroll
                for (int r = 0; r < 4; r++) {
                    const float val = s[n][r] * scale;
                    s[n][r] = (col <= rowg + r) ? val : -1e30f;
                }
            }
        } else {
#pragma unroll
            for (int n = 0; n < 4; n++)
#pragma unroll
                for (int r = 0; r < 4; r++) s[n][r] *= scale;
        }

        // ---- online softmax ----
        float al[4];
#pragma unroll
        for (int r = 0; r < 4; r++) {
            float v0 = fmaxf(fmaxf(s[0][r], s[1][r]), fmaxf(s[2][r], s[3][r]));
            v0 = fmaxf(v0, __shfl_xor(v0, 1));
            v0 = fmaxf(v0, __shfl_xor(v0, 2));
            v0 = fmaxf(v0, __shfl_xor(v0, 4));
            v0 = fmaxf(v0, __shfl_xor(v0, 8));
            const float mn = fmaxf(mprev[r], v0);
            al[r] = __expf(mprev[r] - mn);
            mprev[r] = mn;
        }
#pragma unroll
        for (int r = 0; r < 4; r++) {
            float sum = 0.f;
#pragma unroll
            for (int n = 0; n < 4; n++) {
                const float p = __expf(s[n][r] - mprev[r]);
                sum += p;
                Ps[(w * 16 + g * 4 + r) * PS_STR + n * 16 + m] = f2bf(p);
            }
            sum += __shfl_xor(sum, 1);
            sum += __shfl_xor(sum, 2);
            sum += __shfl_xor(sum, 4);
            sum += __shfl_xor(sum, 8);
            lsum[r] = lsum[r] * al[r] + sum;
        }

        // ---- O = O*alpha + P V ----
#pragma unroll
        for (int dc = 0; dc < 8; dc++)
#pragma unroll
            for (int r = 0; r < 4; r++) o[dc][r] *= al[r];

        // per-wave private Ps rows; same-wave DS ordering suffices (no barrier)
        bf16x8 ap[2];
#pragma unroll
        for (int kk = 0; kk < 2; kk++)
            ap[kk] = *(const bf16x8*)&Ps[(w * 16 + m) * PS_STR + kk * 32 + g * 8];
#pragma unroll
        for (int dc = 0; dc < 8; dc++) {
#pragma unroll
            for (int kk = 0; kk < 2; kk++) {
                const int row = dc * 16 + m;
                bf16x8 bv = *(const bf16x8*)&Vs[(row * 8 + ((kk * 4 + g) ^ sw)) * 8];
                o[dc] = __builtin_amdgcn_mfma_f32_16x16x32_bf16(ap[kk], bv, o[dc], 0, 0, 0);
            }
        }
    }

    // ---- epilogue: normalize, write y bf16 [B, L, H, HD] ----
#pragma unroll
    for (int r = 0; r < 4; r++) {
        const float inv = 1.f / lsum[r];
        const int lrow = q0 + w * 16 + g * 4 + r;
        unsigned short* dst = y + (((size_t)bB * LSEQ + lrow) * NH + hh) * HD;
#pragma unroll
        for (int dc = 0; dc < 8; dc++)
            dst[dc * 16 + m] = f2bf(o[dc][r] * inv);
    }
}

// ---------------------------------------------------------------------------
extern "C" void kernel_launch(void* const* d_in, const int* in_sizes, int n_in,
                              void* d_out, int out_size, void* d_ws, size_t ws_size,
                              hipStream_t stream) {
    const float* x      = (const float*)d_in[0];
    const float* rope   = (const float*)d_in[1];
    const float* w_attn = (const float*)d_in[2];
    const float* w_proj = (const float*)d_in[3];
    float* out = (float*)d_out;
    unsigned short* ws = (unsigned short*)d_ws;

    const size_t per = (size_t)BATCH * NH * LSEQ * HD;  // 8,388,608
    unsigned short* qb  = ws;
    unsigned short* kb  = ws + per;
    unsigned short* vb  = ws + 2 * per;   // transposed layout [B,H,HD,L]
    unsigned short* yb  = ws + 3 * per;
    unsigned short* xb  = ws + 4 * per;
    unsigned short* wab = xb + (size_t)N1;
    unsigned short* wpb = wab + (size_t)N2;

    const int M = BATCH * LSEQ;  // 4096

    // 0) cast inputs to bf16
    const int cast_blocks = (N1 + N2 + N3) / 4 / 256;
    cast_bf16_kernel<<<cast_blocks, 256, 0, stream>>>(x, w_attn, w_proj, xb, wab, wpb);

    // 1) QKV projection (MFMA bf16) + fused RoPE; v written transposed
    dim3 g1(3 * EMB / 128, M / 128);  // (48, 32)
    gemm_bt_bf16<<<g1, 256, 0, stream>>>(xb, wab, rope, nullptr, qb, kb, vb,
                                         M, 3 * EMB, EMB, 1);

    // 2) causal flash attention -> y bf16
    dim3 ga(PTILES, BATCH * NH);  // (32, 32)
    attn_kernel<<<ga, 256, 0, stream>>>(qb, kb, vb, yb);

    // 3) output projection (MFMA bf16) -> fp32 out
    dim3 g2(EMB / 128, M / 128);  // (16, 32)
    gemm_bt_bf16<<<g2, 256, 0, stream>>>(yb, wpb, nullptr, out,
                                         nullptr, nullptr, nullptr, M, EMB, EMB, 0);
}